// Round 2
// baseline (96.740 us; speedup 1.0000x reference)
//
#include <hip/hip_runtime.h>
#include <cstdint>
#include <cstddef>

#define N_NODES 4096
#define IN_DIM  512
#define HEADS   8
#define HID     64
#define OUTF    (HEADS * HID)   // 512
#define SLOPE   0.2f
#define MAXD    1024            // max supported degree (mean ~42; unreachable)

// ---------------- adj dtype detection ----------------
// u8 layout: all 4096 diagonal bytes adj[i*4096+i] are 1  -> sum == 4096.
// i32 layout: byte i*4096+i is byte (i&3) of the int32 at logical (i/4, i/4);
//             only i%4==0 gives 1 (diag low byte)          -> sum == 1024.
// Probe max byte index 16.7M-1 is in-bounds under both layouts.
__global__ __launch_bounds__(256) void detect_adj_dtype(const unsigned char* __restrict__ adj,
                                                        int* __restrict__ flag) {
    __shared__ int cnt[256];
    const int tid = threadIdx.x;
    int c = 0;
    for (int i = tid; i < N_NODES; i += 256)
        c += adj[(size_t)i * N_NODES + i] ? 1 : 0;
    cnt[tid] = c;
    __syncthreads();
    for (int s = 128; s > 0; s >>= 1) {
        if (tid < s) cnt[tid] += cnt[tid + s];
        __syncthreads();
    }
    if (tid == 0) *flag = (cnt[0] == N_NODES) ? 0 : 1;   // 0 = u8, 1 = int32
}

// ---------------- GEMM: g = h @ W  (4096x512 @ 512x512, f32) ----------------
__global__ __launch_bounds__(256) void gemm_f32(const float* __restrict__ A,
                                                const float* __restrict__ B,
                                                float* __restrict__ C) {
    __shared__ float As[16][68];   // [k][m], 68*4=272B rows (17x16B: float4-aligned)
    __shared__ float Bs[16][64];   // [k][n]
    const int tid = threadIdx.x;
    const int tx = tid & 15, ty = tid >> 4;
    const int i0 = blockIdx.y * 64;
    const int j0 = blockIdx.x * 64;
    const int ar = tid >> 2;          // A tile row 0..63
    const int ac = (tid & 3) << 2;    // A tile k 0,4,8,12
    const int bk = tid >> 4;          // B tile k 0..15
    const int bc = (tid & 15) << 2;   // B tile col 0..60
    float acc[4][4] = {};

    for (int k0 = 0; k0 < IN_DIM; k0 += 16) {
        const float4 av = *(const float4*)(A + (size_t)(i0 + ar) * IN_DIM + k0 + ac);
        const float4 bv = *(const float4*)(B + (size_t)(k0 + bk) * OUTF + j0 + bc);
        __syncthreads();
        As[ac + 0][ar] = av.x;
        As[ac + 1][ar] = av.y;
        As[ac + 2][ar] = av.z;
        As[ac + 3][ar] = av.w;
        *(float4*)&Bs[bk][bc] = bv;
        __syncthreads();
#pragma unroll
        for (int k = 0; k < 16; ++k) {
            const float4 a4 = *(const float4*)&As[k][ty << 2];
            const float4 b4 = *(const float4*)&Bs[k][tx << 2];
            const float am[4] = {a4.x, a4.y, a4.z, a4.w};
            const float bn[4] = {b4.x, b4.y, b4.z, b4.w};
#pragma unroll
            for (int m = 0; m < 4; ++m)
#pragma unroll
                for (int n = 0; n < 4; ++n)
                    acc[m][n] = fmaf(am[m], bn[n], acc[m][n]);
        }
    }
#pragma unroll
    for (int m = 0; m < 4; ++m) {
        float4 v = {acc[m][0], acc[m][1], acc[m][2], acc[m][3]};
        *(float4*)(C + (size_t)(i0 + (ty << 2) + m) * OUTF + j0 + (tx << 2)) = v;
    }
}

// ---------------- el/er ----------------
__global__ __launch_bounds__(512) void el_er_kernel(const float* __restrict__ g,
                                                    const float* __restrict__ a,
                                                    float* __restrict__ el,
                                                    float* __restrict__ er) {
    const int i = blockIdx.x;
    const int wid = threadIdx.x >> 6;    // head
    const int lane = threadIdx.x & 63;   // feature
    const float v = g[(size_t)i * OUTF + wid * HID + lane];
    float pl = v * a[lane];
    float pr = v * a[HID + lane];
#pragma unroll
    for (int off = 1; off < 64; off <<= 1) {
        pl += __shfl_xor(pl, off);
        pr += __shfl_xor(pr, off);
    }
    if (lane == 0) {
        el[(size_t)i * HEADS + wid] = pl;
        er[(size_t)i * HEADS + wid] = pr;
    }
}

// ---------------- sparse masked softmax + aggregation ----------------
// One block per row i. 512 threads = 8 waves = 8 heads. Lane = feature.
__global__ __launch_bounds__(512) void gat_attn(const void* __restrict__ adj_raw,
                                                const int* __restrict__ flag,
                                                const float* __restrict__ g,
                                                const float* __restrict__ el,
                                                const float* __restrict__ er,
                                                float* __restrict__ out) {
    const int i = blockIdx.x;
    const int tid = threadIdx.x;
    const int lane = tid & 63;
    const int wid = tid >> 6;   // head

    __shared__ int   nbr[MAXD];
    __shared__ float p[HEADS][MAXD];
    __shared__ int   wave_base[8];
    __shared__ int   s_deg;

    // ---- build 8-bit occupancy mask for this thread's 8 columns ----
    uint32_t msk = 0;
    if (*flag == 0) {   // u8 bool layout
        const uint32_t* row = (const uint32_t*)((const unsigned char*)adj_raw + (size_t)i * N_NODES);
        const uint32_t v0 = row[tid * 2 + 0];
        const uint32_t v1 = row[tid * 2 + 1];
#pragma unroll
        for (int b = 0; b < 4; ++b) {
            if ((v0 >> (8 * b)) & 0xffu) msk |= 1u << b;
            if ((v1 >> (8 * b)) & 0xffu) msk |= 1u << (b + 4);
        }
    } else {            // int32 layout
        const int4* row = (const int4*)((const int*)adj_raw + (size_t)i * N_NODES);
        const int4 w0 = row[tid * 2 + 0];
        const int4 w1 = row[tid * 2 + 1];
        if (w0.x) msk |= 1u;   if (w0.y) msk |= 2u;
        if (w0.z) msk |= 4u;   if (w0.w) msk |= 8u;
        if (w1.x) msk |= 16u;  if (w1.y) msk |= 32u;
        if (w1.z) msk |= 64u;  if (w1.w) msk |= 128u;
    }

    // ---- deterministic compaction: wave scan + block offset ----
    const int c = __popc(msk);
    int inc = c;
#pragma unroll
    for (int off = 1; off < 64; off <<= 1) {
        const int t = __shfl_up(inc, off);
        if (lane >= off) inc += t;
    }
    if (lane == 63) wave_base[wid] = inc;
    __syncthreads();
    if (tid == 0) {
        int run = 0;
#pragma unroll
        for (int w = 0; w < 8; ++w) { const int t = wave_base[w]; wave_base[w] = run; run += t; }
        s_deg = run;
    }
    __syncthreads();
    int pos = wave_base[wid] + inc - c;
#pragma unroll
    for (int b = 0; b < 8; ++b) {
        if (msk & (1u << b)) {
            if (pos < MAXD) nbr[pos] = tid * 8 + b;
            ++pos;
        }
    }
    __syncthreads();
    const int deg = min(s_deg, MAXD);   // >=1 (diagonal)

    // ---- per-head softmax over neighbor list ----
    const float eli = el[(size_t)i * HEADS + wid];
    float m = -1e30f;
    for (int j = lane; j < deg; j += 64) {
        float e = eli + er[(size_t)nbr[j] * HEADS + wid];
        e = (e >= 0.f) ? e : SLOPE * e;
        m = fmaxf(m, e);
    }
#pragma unroll
    for (int off = 1; off < 64; off <<= 1) m = fmaxf(m, __shfl_xor(m, off));

    float s = 0.f;
    for (int j = lane; j < deg; j += 64) {
        float e = eli + er[(size_t)nbr[j] * HEADS + wid];
        e = (e >= 0.f) ? e : SLOPE * e;
        const float pe = __expf(e - m);
        p[wid][j] = pe;
        s += pe;
    }
#pragma unroll
    for (int off = 1; off < 64; off <<= 1) s += __shfl_xor(s, off);
    const float inv = 1.f / s;
    __syncthreads();   // p[] visibility across lanes of each wave

    // ---- weighted gather: lane = feature ----
    float acc = 0.f;
    const float* gh = g + (size_t)wid * HID + lane;
#pragma unroll 4
    for (int j = 0; j < deg; ++j) {
        acc = fmaf(p[wid][j], gh[(size_t)nbr[j] * OUTF], acc);
    }
    out[(size_t)i * OUTF + wid * HID + lane] = acc * inv;
}

extern "C" void kernel_launch(void* const* d_in, const int* in_sizes, int n_in,
                              void* d_out, int out_size, void* d_ws, size_t ws_size,
                              hipStream_t stream) {
    const float* h   = (const float*)d_in[0];
    const void*  adj = d_in[1];
    const float* W   = (const float*)d_in[2];
    const float* a   = (const float*)d_in[3];
    float* out = (float*)d_out;

    float* g    = (float*)d_ws;                        // 4096*512 f32 = 8 MB
    float* el   = g + (size_t)N_NODES * OUTF;
    float* er   = el + (size_t)N_NODES * HEADS;
    int*   flag = (int*)(er + (size_t)N_NODES * HEADS);

    detect_adj_dtype<<<1, 256, 0, stream>>>((const unsigned char*)adj, flag);
    dim3 gemm_grid(OUTF / 64, N_NODES / 64);           // (8, 64)
    gemm_f32<<<gemm_grid, 256, 0, stream>>>(h, W, g);
    el_er_kernel<<<N_NODES, 512, 0, stream>>>(g, a, el, er);
    gat_attn<<<N_NODES, 512, 0, stream>>>(adj, flag, g, el, er, out);
}